// Round 7
// baseline (476.479 us; speedup 1.0000x reference)
//
#include <hip/hip_runtime.h>
#include <math.h>

#define NN 512
#define HD 256
#define NLAYER 6
#define QSCALE 0.17677669529663687f
#define NBLK 128

typedef __attribute__((ext_vector_type(8))) short bf16x8;
typedef __attribute__((ext_vector_type(4))) short bf16x4;
typedef __attribute__((ext_vector_type(4))) float f32x4;

__device__ __forceinline__ short f2bf(float f) {
  union { float f; unsigned u; } v; v.f = f;
  unsigned r = (v.u + 0x7FFFu + ((v.u >> 16) & 1u)) >> 16;
  return (short)r;
}
__device__ __forceinline__ float bf2f(short s) {
  union { unsigned u; float f; } v; v.u = ((unsigned)(unsigned short)s) << 16;
  return v.f;
}

// ---- device-scope grid barrier (all NBLK blocks resident by construction) ----
__device__ __forceinline__ void gbar(unsigned* cnt, unsigned* gen, unsigned g) {
  __syncthreads();
  if (threadIdx.x == 0) {
    __threadfence();   // publish this block's writes (L2 wb to coherent point)
    unsigned old = __hip_atomic_fetch_add(cnt, 1u, __ATOMIC_RELAXED,
                                          __HIP_MEMORY_SCOPE_AGENT);
    if (old == (unsigned)(NBLK - 1)) {
      __hip_atomic_store(cnt, 0u, __ATOMIC_RELAXED, __HIP_MEMORY_SCOPE_AGENT);
      __hip_atomic_store(gen, g + 1u, __ATOMIC_RELEASE, __HIP_MEMORY_SCOPE_AGENT);
    } else {
      unsigned cur;
      do {
        __builtin_amdgcn_s_sleep(2);
        cur = __hip_atomic_load(gen, __ATOMIC_RELAXED, __HIP_MEMORY_SCOPE_AGENT);
      } while (cur < g + 1u);
    }
    __threadfence();   // acquire: invalidate stale cache before next stage
  }
  __syncthreads();
}

#define GBAR() do { gbar(bcnt, bgen, g); ++g; } while (0)

__global__ __launch_bounds__(512) void mono_kernel(
    const float* __restrict__ x,
    const int* __restrict__ ee, const int* __restrict__ ed,
    const float* __restrict__ Wf, const float* __restrict__ b_feat,
    const float* __restrict__ edge_emb, const float* __restrict__ edge_dist_emb,
    const float* __restrict__ W_ee, const float* __restrict__ b_ee,
    const float* __restrict__ W_ed, const float* __restrict__ b_ed,
    const float* __restrict__ ln1_s, const float* __restrict__ ln1_b,
    const float* __restrict__ Wq, const float* __restrict__ bq,
    const float* __restrict__ Wk, const float* __restrict__ bk,
    const float* __restrict__ Wv, const float* __restrict__ bv,
    const float* __restrict__ Wo, const float* __restrict__ bo,
    const float* __restrict__ ln2_s, const float* __restrict__ ln2_b,
    const float* __restrict__ W1, const float* __restrict__ b1,
    const float* __restrict__ W2, const float* __restrict__ b2,
    float* __restrict__ h,
    short* __restrict__ bias_bf, short* __restrict__ Aqkv,
    short* __restrict__ AoT, short* __restrict__ A1T, short* __restrict__ A2T,
    short* __restrict__ WfT,
    short* __restrict__ q_bf, short* __restrict__ k_bf, short* __restrict__ vT_bf,
    short* __restrict__ o_bf, short* __restrict__ g_bf,
    float* __restrict__ eeP, float* __restrict__ edP,
    unsigned* __restrict__ bcnt, unsigned* __restrict__ bgen) {
  __shared__ __align__(16) char lds_raw[33536];
  int tid = threadIdx.x, bid = blockIdx.x;
  int w = tid >> 6, l = tid & 63, lr = l & 15, lk = l >> 4;
  unsigned g = 0;

  // ================= S0: wcast (all blocks) + proj (first 160 waves) ========
  {
    float* tileb = (float*)lds_raw;           // [2][32*33]
    int half = tid >> 8, tu = tid & 255;
    float* tile = tileb + half * (32 * 33);
    for (int it = 0; it < 10; ++it) {
      int u = it * 256 + bid * 2 + half;
      bool act = (u < 2368);
      const float* src = Wf; short* dst = WfT; float scl = 1.f; int t = 0;
      if (act) {
        if (u < 2304) {
          int ll = u / 384, rr = u % 384, mat = rr / 64; t = rr % 64;
          if      (mat == 0) { src = Wq + ll * 65536; dst = Aqkv + ll * 196608; scl = QSCALE; }
          else if (mat == 1) { src = Wk + ll * 65536; dst = Aqkv + ll * 196608 + 65536; }
          else if (mat == 2) { src = Wv + ll * 65536; dst = Aqkv + ll * 196608 + 131072; }
          else if (mat == 3) { src = Wo + ll * 65536; dst = AoT + ll * 65536; }
          else if (mat == 4) { src = W1 + ll * 65536; dst = A1T + ll * 65536; }
          else               { src = W2 + ll * 65536; dst = A2T + ll * 65536; }
        } else { src = Wf; dst = WfT; t = u - 2304; }
      }
      int tr = t >> 3, tc = t & 7;
      int kl = tu >> 3, nl4 = (tu & 7) * 4;
      float4 v = make_float4(0.f, 0.f, 0.f, 0.f);
      if (act) v = *(const float4*)(src + (tr * 32 + kl) * 256 + tc * 32 + nl4);
      __syncthreads();                       // prior iter reads done
      tile[kl * 33 + nl4 + 0] = v.x; tile[kl * 33 + nl4 + 1] = v.y;
      tile[kl * 33 + nl4 + 2] = v.z; tile[kl * 33 + nl4 + 3] = v.w;
      __syncthreads();
      if (act) {
        int nl = tu >> 3, kl4 = (tu & 7) * 4;
        bf16x4 o;
        #pragma unroll
        for (int i = 0; i < 4; i++) o[i] = f2bf(tile[(kl4 + i) * 33 + nl] * scl);
        *(bf16x4*)(dst + (tc * 32 + nl) * 256 + tr * 32 + kl4) = o;
      }
    }
    // proj: one wave per table row (160 rows)
    int gid = bid * 8 + w;
    if (gid < 160) {
      const float* table; const float* W; float* out; int row;
      if (gid < 32) { table = edge_emb;      W = W_ee; out = eeP; row = gid; }
      else          { table = edge_dist_emb; W = W_ed; out = edP; row = gid - 32; }
      float4 v4 = *(const float4*)(table + row * 256 + l * 4);
      float ss = v4.x * v4.x + v4.y * v4.y + v4.z * v4.z + v4.w * v4.w;
      #pragma unroll
      for (int o = 32; o; o >>= 1) ss += __shfl_xor(ss, o);
      float n = sqrtf(ss);
      float sc = (n > 1.f) ? 1.f / (n + 1e-7f) : 1.f;
      float vv[4] = {v4.x * sc, v4.y * sc, v4.z * sc, v4.w * sc};
      #pragma unroll
      for (int hh = 0; hh < 8; hh++) {
        float p = 0.f;
        #pragma unroll
        for (int i = 0; i < 4; i++) p += vv[i] * W[(l * 4 + i) * 8 + hh];
        #pragma unroll
        for (int o = 32; o; o >>= 1) p += __shfl_xor(p, o);
        if (l == 0) out[row * 8 + hh] = p;
      }
    }
  }
  GBAR();

  // ================= S1: bias (blocks 0-63) | feat (blocks 64-127) ==========
  if (bid < 64) {
    float* seeP = (float*)lds_raw;            // 256
    float* sedP = seeP + 256;                 // 1024
    float* sbe  = sedP + 1024;                // 8
    float* sbd  = sbe + 8;                    // 8
    if (tid < 256) seeP[tid] = eeP[tid];
    sedP[tid] = edP[tid]; sedP[tid + 512] = edP[tid + 512];
    if (tid < 8) { sbe[tid] = b_ee[tid]; sbd[tid] = b_ed[tid]; }
    __syncthreads();
    int half = tid >> 8, tu = tid & 255;
    for (int it = 0; it < 8; ++it) {
      int u = bid * 2 + half + it * 128;
      int idx = u * 256 + tu;
      int e0 = ee[idx * 2], e1 = ee[idx * 2 + 1];
      int d = ed[idx];
      #pragma unroll
      for (int hh = 0; hh < 8; hh++) {
        bias_bf[hh * (NN * NN) + idx] = f2bf(
            0.5f * (seeP[e0 * 8 + hh] + seeP[e1 * 8 + hh]) + sbe[hh]
            + sedP[d * 8 + hh] + sbd[hh]);
      }
    }
  } else {
    int gid = (bid - 64) * 8 + w;             // 0..511
    int mt = gid >> 4, nt = gid & 15;
    f32x4 acc = {};
    for (int k0 = 0; k0 < 256; k0 += 32) {
      const float4* px = (const float4*)(x + (mt * 16 + lr) * 256 + k0 + lk * 8);
      float4 a0 = px[0], a1 = px[1];
      bf16x8 va;
      va[0] = f2bf(a0.x); va[1] = f2bf(a0.y); va[2] = f2bf(a0.z); va[3] = f2bf(a0.w);
      va[4] = f2bf(a1.x); va[5] = f2bf(a1.y); va[6] = f2bf(a1.z); va[7] = f2bf(a1.w);
      bf16x8 vb = *(const bf16x8*)(WfT + (nt * 16 + lr) * 256 + k0 + lk * 8);
      acc = __builtin_amdgcn_mfma_f32_16x16x32_bf16(va, vb, acc, 0, 0, 0);
    }
    int n = nt * 16 + lr;
    #pragma unroll
    for (int r = 0; r < 4; r++)
      h[(mt * 16 + lk * 4 + r) * 256 + n] = acc[r] + b_feat[n];
  }
  GBAR();

  // ================= layers =================================================
  for (int layer = 0; layer < NLAYER; ++layer) {
    const short* Aqkv_l = Aqkv + layer * 196608;
    const short* AoT_l  = AoT + layer * 65536;
    const short* A1T_l  = A1T + layer * 65536;
    const short* A2T_l  = A2T + layer * 65536;

    // ---- LN1 (recompute per block) + QKV ----
    {
      int rt = bid >> 2, q4 = bid & 3;
      short* y = (short*)lds_raw;             // [16][256] bf16
      if (tid < 256) {
        int row = tid >> 4, j = tid & 15;
        const float* rp = h + (rt * 16 + row) * 256 + j * 16;
        float loc[16]; float sum = 0.f;
        #pragma unroll
        for (int i = 0; i < 16; i++) { loc[i] = rp[i]; sum += loc[i]; }
        #pragma unroll
        for (int o = 8; o; o >>= 1) sum += __shfl_xor(sum, o, 16);
        float mean = sum * (1.f / 256.f);
        float var = 0.f;
        #pragma unroll
        for (int i = 0; i < 16; i++) { float d = loc[i] - mean; var += d * d; }
        #pragma unroll
        for (int o = 8; o; o >>= 1) var += __shfl_xor(var, o, 16);
        float inv = rsqrtf(var * (1.f / 256.f) + 1e-5f);
        const float* s = ln1_s + layer * HD;
        const float* b = ln1_b + layer * HD;
        #pragma unroll
        for (int i = 0; i < 16; i++)
          y[row * 256 + j * 16 + i] =
              f2bf((loc[i] - mean) * inv * s[j * 16 + i] + b[j * 16 + i]);
      }
      __syncthreads();
      const float* bq_l = bq + layer * HD;
      const float* bk_l = bk + layer * HD;
      const float* bv_l = bv + layer * HD;
      for (int ct = q4 * 12 + w; ct < q4 * 12 + 12; ct += 8) {
        f32x4 acc = {};
        for (int k0 = 0; k0 < 256; k0 += 32) {
          bf16x8 af = *(const bf16x8*)(y + lr * 256 + k0 + lk * 8);
          bf16x8 bfr = *(const bf16x8*)(Aqkv_l + (ct * 16 + lr) * 256 + k0 + lk * 8);
          acc = __builtin_amdgcn_mfma_f32_16x16x32_bf16(af, bfr, acc, 0, 0, 0);
        }
        int n = ct * 16 + lr;
        #pragma unroll
        for (int r = 0; r < 4; r++) {
          int gm = rt * 16 + lk * 4 + r;
          float v = acc[r];
          if (n < 256) {
            q_bf[((n >> 5) * 512 + gm) * 32 + (n & 31)] = f2bf(v + bq_l[n] * QSCALE);
          } else if (n < 512) {
            int nn = n - 256;
            k_bf[((nn >> 5) * 512 + gm) * 32 + (nn & 31)] = f2bf(v + bk_l[nn]);
          } else {
            int nn = n - 512;
            vT_bf[nn * 512 + gm] = f2bf(v + bv_l[nn]);
          }
        }
      }
    }
    GBAR();

    // ---- attention: 2 units (head, rowtile) per block ----
    {
      int unit = tid >> 8, tu = tid & 255, wu = w & 3;
      int hrt = bid * 2 + unit;
      int head = hrt >> 5, rt = hrt & 31;
      short* Sb = (short*)lds_raw + unit * (16 * 520);
      bf16x8 aq = *(const bf16x8*)(q_bf + (head * 512 + rt * 16 + lr) * 32 + lk * 8);
      #pragma unroll 2
      for (int j = 0; j < 8; j++) {
        int node0 = wu * 128 + j * 16;
        bf16x8 bk8 = *(const bf16x8*)(k_bf + (head * 512 + node0 + lr) * 32 + lk * 8);
        f32x4 s = {};
        s = __builtin_amdgcn_mfma_f32_16x16x32_bf16(aq, bk8, s, 0, 0, 0);
        int gnode = node0 + lr;
        #pragma unroll
        for (int r = 0; r < 4; r++) {
          int row = lk * 4 + r;
          float logit = s[r] + bf2f(bias_bf[(head * 512 + rt * 16 + row) * 512 + gnode]);
          Sb[row * 520 + gnode] = f2bf(logit);
        }
      }
      __syncthreads();
      {
        int row = tu >> 4, j = tu & 15;
        short* Srow = Sb + row * 520;
        float mx = -1e30f;
        #pragma unroll 8
        for (int t = 0; t < 32; t++) mx = fmaxf(mx, bf2f(Srow[j + t * 16]));
        #pragma unroll
        for (int o = 8; o; o >>= 1) mx = fmaxf(mx, __shfl_xor(mx, o, 16));
        float sum = 0.f;
        #pragma unroll 8
        for (int t = 0; t < 32; t++) sum += __expf(bf2f(Srow[j + t * 16]) - mx);
        #pragma unroll
        for (int o = 8; o; o >>= 1) sum += __shfl_xor(sum, o, 16);
        float inv = 1.f / sum;
        #pragma unroll 8
        for (int t = 0; t < 32; t++)
          Srow[j + t * 16] = f2bf(__expf(bf2f(Srow[j + t * 16]) - mx) * inv);
      }
      __syncthreads();
      if (wu < 2) {
        int dh = wu;
        f32x4 oc = {};
        #pragma unroll 4
        for (int ch = 0; ch < 16; ch++) {
          bf16x8 ap = *(const bf16x8*)(Sb + lr * 520 + ch * 32 + lk * 8);
          bf16x8 bv8 = *(const bf16x8*)(vT_bf + (head * 32 + dh * 16 + lr) * 512 + ch * 32 + lk * 8);
          oc = __builtin_amdgcn_mfma_f32_16x16x32_bf16(ap, bv8, oc, 0, 0, 0);
        }
        #pragma unroll
        for (int r = 0; r < 4; r++)
          o_bf[(rt * 16 + lk * 4 + r) * 256 + head * 32 + dh * 16 + lr] = f2bf(oc[r]);
      }
    }
    GBAR();

    // ---- O-proj + residual (flat 512 tiles) ----
    {
      int gid = bid * 8 + w;
      if (gid < 512) {
        int mt = gid >> 4, nt = gid & 15;
        const float* bo_l = bo + layer * HD;
        f32x4 acc = {};
        for (int k0 = 0; k0 < 256; k0 += 32) {
          bf16x8 af = *(const bf16x8*)(o_bf + (mt * 16 + lr) * 256 + k0 + lk * 8);
          bf16x8 bfr = *(const bf16x8*)(AoT_l + (nt * 16 + lr) * 256 + k0 + lk * 8);
          acc = __builtin_amdgcn_mfma_f32_16x16x32_bf16(af, bfr, acc, 0, 0, 0);
        }
        int n = nt * 16 + lr;
        #pragma unroll
        for (int r = 0; r < 4; r++) {
          int m = mt * 16 + lk * 4 + r;
          h[m * 256 + n] = h[m * 256 + n] + acc[r] + bo_l[n];
        }
      }
    }
    GBAR();

    // ---- LN2 (recompute) + FFN1 + gelu ----
    {
      int rt = bid >> 2, q4 = bid & 3;
      short* y = (short*)lds_raw;             // 8 KB
      float* part = (float*)(lds_raw + 8192); // [4][256] f32
      if (tid < 256) {
        int row = tid >> 4, j = tid & 15;
        const float* rp = h + (rt * 16 + row) * 256 + j * 16;
        float loc[16]; float sum = 0.f;
        #pragma unroll
        for (int i = 0; i < 16; i++) { loc[i] = rp[i]; sum += loc[i]; }
        #pragma unroll
        for (int o = 8; o; o >>= 1) sum += __shfl_xor(sum, o, 16);
        float mean = sum * (1.f / 256.f);
        float var = 0.f;
        #pragma unroll
        for (int i = 0; i < 16; i++) { float d = loc[i] - mean; var += d * d; }
        #pragma unroll
        for (int o = 8; o; o >>= 1) var += __shfl_xor(var, o, 16);
        float inv = rsqrtf(var * (1.f / 256.f) + 1e-5f);
        const float* s = ln2_s + layer * HD;
        const float* b = ln2_b + layer * HD;
        #pragma unroll
        for (int i = 0; i < 16; i++)
          y[row * 256 + j * 16 + i] =
              f2bf((loc[i] - mean) * inv * s[j * 16 + i] + b[j * 16 + i]);
      }
      __syncthreads();
      int ct = q4 * 4 + (w & 3), kh = w >> 2;
      f32x4 acc = {};
      for (int ks = 0; ks < 4; ks++) {
        int k0 = kh * 128 + ks * 32;
        bf16x8 af = *(const bf16x8*)(y + lr * 256 + k0 + lk * 8);
        bf16x8 bfr = *(const bf16x8*)(A1T_l + (ct * 16 + lr) * 256 + k0 + lk * 8);
        acc = __builtin_amdgcn_mfma_f32_16x16x32_bf16(af, bfr, acc, 0, 0, 0);
      }
      if (kh == 1) {
        #pragma unroll
        for (int r = 0; r < 4; r++)
          part[(w & 3) * 256 + (lk * 4 + r) * 16 + lr] = acc[r];
      }
      __syncthreads();
      if (kh == 0) {
        const float* b1_l = b1 + layer * HD;
        int n = ct * 16 + lr;
        #pragma unroll
        for (int r = 0; r < 4; r++) {
          float val = acc[r] + part[(w & 3) * 256 + (lk * 4 + r) * 16 + lr] + b1_l[n];
          g_bf[(rt * 16 + lk * 4 + r) * 256 + n] =
              f2bf(0.5f * val * (1.f + erff(val * 0.70710678118654752f)));
        }
      }
    }
    GBAR();

    // ---- FFN2 + residual (flat 512 tiles) ----
    {
      int gid = bid * 8 + w;
      if (gid < 512) {
        int mt = gid >> 4, nt = gid & 15;
        const float* b2_l = b2 + layer * HD;
        f32x4 acc = {};
        for (int k0 = 0; k0 < 256; k0 += 32) {
          bf16x8 af = *(const bf16x8*)(g_bf + (mt * 16 + lr) * 256 + k0 + lk * 8);
          bf16x8 bfr = *(const bf16x8*)(A2T_l + (nt * 16 + lr) * 256 + k0 + lk * 8);
          acc = __builtin_amdgcn_mfma_f32_16x16x32_bf16(af, bfr, acc, 0, 0, 0);
        }
        int n = nt * 16 + lr;
        #pragma unroll
        for (int r = 0; r < 4; r++) {
          int m = mt * 16 + lk * 4 + r;
          h[m * 256 + n] = h[m * 256 + n] + acc[r] + b2_l[n];
        }
      }
    }
    if (layer != NLAYER - 1) GBAR();
  }
}

extern "C" void kernel_launch(void* const* d_in, const int* in_sizes, int n_in,
                              void* d_out, int out_size, void* d_ws, size_t ws_size,
                              hipStream_t stream) {
  const float* x             = (const float*)d_in[0];
  const int*   edge_encodes  = (const int*)d_in[2];
  const int*   edge_dist_enc = (const int*)d_in[3];
  const float* W_feat = (const float*)d_in[7];
  const float* b_feat = (const float*)d_in[8];
  const float* edge_emb      = (const float*)d_in[9];
  const float* edge_dist_emb = (const float*)d_in[10];
  const float* W_ee = (const float*)d_in[11];
  const float* b_ee = (const float*)d_in[12];
  const float* W_ed = (const float*)d_in[13];
  const float* b_ed = (const float*)d_in[14];
  const float* ln1_s = (const float*)d_in[15];
  const float* ln1_b = (const float*)d_in[16];
  const float* Wq = (const float*)d_in[17];
  const float* bq = (const float*)d_in[18];
  const float* Wk = (const float*)d_in[19];
  const float* bk = (const float*)d_in[20];
  const float* Wv = (const float*)d_in[21];
  const float* bv = (const float*)d_in[22];
  const float* Wo = (const float*)d_in[23];
  const float* bo = (const float*)d_in[24];
  const float* ln2_s = (const float*)d_in[25];
  const float* ln2_b = (const float*)d_in[26];
  const float* W1 = (const float*)d_in[27];
  const float* b1 = (const float*)d_in[28];
  const float* W2 = (const float*)d_in[29];
  const float* b2 = (const float*)d_in[30];

  float* h = (float*)d_out;
  char* base = (char*)d_ws;
  short* bias_bf = (short*)base;                       // 4 MB
  short* Aqkv = (short*)(base + 4194304);
  short* AoT  = (short*)(base + 6553600);
  short* A1T  = (short*)(base + 7340032);
  short* A2T  = (short*)(base + 8126464);
  short* WfT  = (short*)(base + 8912896);
  short* q_bf = (short*)(base + 9043968);
  short* k_bf = (short*)(base + 9306112);
  short* vT_bf= (short*)(base + 9568256);
  short* o_bf = (short*)(base + 9830400);
  short* g_bf = (short*)(base + 10092544);
  float* eeP  = (float*)(base + 10354688);
  float* edP  = (float*)(base + 10355712);
  unsigned* bar = (unsigned*)(base + 10359808);

  hipMemsetAsync(bar, 0, 64, stream);
  mono_kernel<<<NBLK, 512, 0, stream>>>(
      x, edge_encodes, edge_dist_enc, W_feat, b_feat,
      edge_emb, edge_dist_emb, W_ee, b_ee, W_ed, b_ed,
      ln1_s, ln1_b, Wq, bq, Wk, bk, Wv, bv, Wo, bo,
      ln2_s, ln2_b, W1, b1, W2, b2,
      h, bias_bf, Aqkv, AoT, A1T, A2T, WfT,
      q_bf, k_bf, vT_bf, o_bf, g_bf, eeP, edP,
      bar, bar + 1);
}

// Round 8
// 409.636 us; speedup vs baseline: 1.1632x; 1.1632x over previous
//
#include <hip/hip_runtime.h>
#include <math.h>

#define NN 512
#define HD 256
#define NLAYER 6
#define QSCALE 0.17677669529663687f
#define NBLK 128
#define ASTR 264   // padded activation LDS stride (shorts): bank-conflict-free

typedef __attribute__((ext_vector_type(8))) short bf16x8;
typedef __attribute__((ext_vector_type(4))) short bf16x4;
typedef __attribute__((ext_vector_type(4))) float f32x4;

__device__ __forceinline__ short f2bf(float f) {
  union { float f; unsigned u; } v; v.f = f;
  unsigned r = (v.u + 0x7FFFu + ((v.u >> 16) & 1u)) >> 16;
  return (short)r;
}
__device__ __forceinline__ float bf2f(short s) {
  union { unsigned u; float f; } v; v.u = ((unsigned)(unsigned short)s) << 16;
  return v.f;
}

// ---- contention-free grid barrier: per-block flags + block-0 aggregator ----
__device__ __forceinline__ void gbar(unsigned* flags, unsigned* gen, unsigned g) {
  __syncthreads();
  int tid = threadIdx.x, bid = blockIdx.x;
  if (bid == 0) {
    if (tid > 0 && tid < NBLK) {
      unsigned cur;
      do {
        __builtin_amdgcn_s_sleep(1);
        cur = __hip_atomic_load(flags + tid * 16, __ATOMIC_RELAXED,
                                __HIP_MEMORY_SCOPE_AGENT);
      } while (cur < g);
    }
    __syncthreads();
    if (tid == 0) {
      __threadfence();
      __hip_atomic_store(gen, g, __ATOMIC_RELEASE, __HIP_MEMORY_SCOPE_AGENT);
    }
  } else {
    if (tid == 0) {
      __threadfence();
      __hip_atomic_store(flags + bid * 16, g, __ATOMIC_RELEASE,
                         __HIP_MEMORY_SCOPE_AGENT);
      unsigned cur;
      do {
        __builtin_amdgcn_s_sleep(1);
        cur = __hip_atomic_load(gen, __ATOMIC_RELAXED, __HIP_MEMORY_SCOPE_AGENT);
      } while (cur < g);
      __threadfence();
    }
  }
  __syncthreads();
}

#define GBAR() do { gbar(flags, gen, g); ++g; } while (0)

__global__ __launch_bounds__(512) void mono_kernel(
    const float* __restrict__ x,
    const int* __restrict__ ee, const int* __restrict__ ed,
    const float* __restrict__ Wf, const float* __restrict__ b_feat,
    const float* __restrict__ edge_emb, const float* __restrict__ edge_dist_emb,
    const float* __restrict__ W_ee, const float* __restrict__ b_ee,
    const float* __restrict__ W_ed, const float* __restrict__ b_ed,
    const float* __restrict__ ln1_s, const float* __restrict__ ln1_b,
    const float* __restrict__ Wq, const float* __restrict__ bq,
    const float* __restrict__ Wk, const float* __restrict__ bk,
    const float* __restrict__ Wv, const float* __restrict__ bv,
    const float* __restrict__ Wo, const float* __restrict__ bo,
    const float* __restrict__ ln2_s, const float* __restrict__ ln2_b,
    const float* __restrict__ W1, const float* __restrict__ b1,
    const float* __restrict__ W2, const float* __restrict__ b2,
    float* __restrict__ h,
    short* __restrict__ bias_bf, short* __restrict__ Aqkv,
    short* __restrict__ AoT, short* __restrict__ A1T, short* __restrict__ A2T,
    short* __restrict__ WfT,
    short* __restrict__ q_bf, short* __restrict__ k_bf, short* __restrict__ vT_bf,
    short* __restrict__ o_bf,
    float* __restrict__ eeP, float* __restrict__ edP,
    unsigned* __restrict__ flags, unsigned* __restrict__ gen) {
  __shared__ __align__(16) char lds_raw[33536];
  int tid = threadIdx.x, bid = blockIdx.x;
  int w = tid >> 6, l = tid & 63, lr = l & 15, lk = l >> 4;
  unsigned g = 1;

  // ================= S0: wcast (all blocks) + proj (first 160 waves) ========
  {
    float* tileb = (float*)lds_raw;
    int half = tid >> 8, tu = tid & 255;
    float* tile = tileb + half * (32 * 33);
    for (int it = 0; it < 10; ++it) {
      int u = it * 256 + bid * 2 + half;
      bool act = (u < 2368);
      const float* src = Wf; short* dst = WfT; float scl = 1.f; int t = 0;
      if (act) {
        if (u < 2304) {
          int ll = u / 384, rr = u % 384, mat = rr / 64; t = rr % 64;
          if      (mat == 0) { src = Wq + ll * 65536; dst = Aqkv + ll * 196608; scl = QSCALE; }
          else if (mat == 1) { src = Wk + ll * 65536; dst = Aqkv + ll * 196608 + 65536; }
          else if (mat == 2) { src = Wv + ll * 65536; dst = Aqkv + ll * 196608 + 131072; }
          else if (mat == 3) { src = Wo + ll * 65536; dst = AoT + ll * 65536; }
          else if (mat == 4) { src = W1 + ll * 65536; dst = A1T + ll * 65536; }
          else               { src = W2 + ll * 65536; dst = A2T + ll * 65536; }
        } else { src = Wf; dst = WfT; t = u - 2304; }
      }
      int tr = t >> 3, tc = t & 7;
      int kl = tu >> 3, nl4 = (tu & 7) * 4;
      float4 v = make_float4(0.f, 0.f, 0.f, 0.f);
      if (act) v = *(const float4*)(src + (tr * 32 + kl) * 256 + tc * 32 + nl4);
      __syncthreads();
      tile[kl * 33 + nl4 + 0] = v.x; tile[kl * 33 + nl4 + 1] = v.y;
      tile[kl * 33 + nl4 + 2] = v.z; tile[kl * 33 + nl4 + 3] = v.w;
      __syncthreads();
      if (act) {
        int nl = tu >> 3, kl4 = (tu & 7) * 4;
        bf16x4 o;
        #pragma unroll
        for (int i = 0; i < 4; i++) o[i] = f2bf(tile[(kl4 + i) * 33 + nl] * scl);
        *(bf16x4*)(dst + (tc * 32 + nl) * 256 + tr * 32 + kl4) = o;
      }
    }
    int gid = bid * 8 + w;
    if (gid < 160) {
      const float* table; const float* W; float* out; int row;
      if (gid < 32) { table = edge_emb;      W = W_ee; out = eeP; row = gid; }
      else          { table = edge_dist_emb; W = W_ed; out = edP; row = gid - 32; }
      float4 v4 = *(const float4*)(table + row * 256 + l * 4);
      float ss = v4.x * v4.x + v4.y * v4.y + v4.z * v4.z + v4.w * v4.w;
      #pragma unroll
      for (int o = 32; o; o >>= 1) ss += __shfl_xor(ss, o);
      float n = sqrtf(ss);
      float sc = (n > 1.f) ? 1.f / (n + 1e-7f) : 1.f;
      float vv[4] = {v4.x * sc, v4.y * sc, v4.z * sc, v4.w * sc};
      #pragma unroll
      for (int hh = 0; hh < 8; hh++) {
        float p = 0.f;
        #pragma unroll
        for (int i = 0; i < 4; i++) p += vv[i] * W[(l * 4 + i) * 8 + hh];
        #pragma unroll
        for (int o = 32; o; o >>= 1) p += __shfl_xor(p, o);
        if (l == 0) out[row * 8 + hh] = p;
      }
    }
  }
  GBAR();

  // ===== S1: bias (blocks 0-63) | feat+LN1+QKV0, 8 rows/block (64-127) ======
  if (bid < 64) {
    float* seeP = (float*)lds_raw;
    float* sedP = seeP + 256;
    float* sbe  = sedP + 1024;
    float* sbd  = sbe + 8;
    if (tid < 256) seeP[tid] = eeP[tid];
    sedP[tid] = edP[tid]; sedP[tid + 512] = edP[tid + 512];
    if (tid < 8) { sbe[tid] = b_ee[tid]; sbd[tid] = b_ed[tid]; }
    __syncthreads();
    int half = tid >> 8, tu = tid & 255;
    for (int it = 0; it < 8; ++it) {
      int u = bid * 2 + half + it * 128;
      int idx = u * 256 + tu;
      int e0 = ee[idx * 2], e1 = ee[idx * 2 + 1];
      int d = ed[idx];
      #pragma unroll
      for (int hh = 0; hh < 8; hh++) {
        bias_bf[hh * (NN * NN) + idx] = f2bf(
            0.5f * (seeP[e0 * 8 + hh] + seeP[e1 * 8 + hh]) + sbe[hh]
            + sedP[d * 8 + hh] + sbd[hh]);
      }
    }
  } else {
    int m0 = (bid - 64) * 8;
    short* Abuf = (short*)lds_raw;                 // [16][ASTR]
    float* hbuf = (float*)(lds_raw + 8448);        // [8][256]
    if (tid < 264) {
      bf16x8 z = {};
      *(bf16x8*)(Abuf + 8 * ASTR + tid * 8) = z;   // zero rows 8..15
    }
    {
      int row = tid >> 6, j = tid & 63;
      float4 v = *(const float4*)(x + (m0 + row) * 256 + j * 4);
      bf16x4 o4; o4[0] = f2bf(v.x); o4[1] = f2bf(v.y); o4[2] = f2bf(v.z); o4[3] = f2bf(v.w);
      *(bf16x4*)(Abuf + row * ASTR + j * 4) = o4;
    }
    __syncthreads();
    {
      f32x4 acc[2] = {};
      int nb = w * 32;
      for (int k0 = 0; k0 < 256; k0 += 32) {
        bf16x8 af = *(const bf16x8*)(Abuf + lr * ASTR + k0 + lk * 8);
        bf16x8 b0 = *(const bf16x8*)(WfT + (nb + lr) * 256 + k0 + lk * 8);
        bf16x8 b1f = *(const bf16x8*)(WfT + (nb + 16 + lr) * 256 + k0 + lk * 8);
        acc[0] = __builtin_amdgcn_mfma_f32_16x16x32_bf16(af, b0, acc[0], 0, 0, 0);
        acc[1] = __builtin_amdgcn_mfma_f32_16x16x32_bf16(af, b1f, acc[1], 0, 0, 0);
      }
      #pragma unroll
      for (int t = 0; t < 2; t++) {
        int n = nb + t * 16 + lr;
        #pragma unroll
        for (int r = 0; r < 4; r++) {
          int m = lk * 4 + r;
          if (m < 8) {
            float v = acc[t][r] + b_feat[n];
            hbuf[m * 256 + n] = v;
            h[(m0 + m) * 256 + n] = v;
          }
        }
      }
    }
    __syncthreads();
    {  // LN1: wave w -> row w
      float4 v4 = *(const float4*)(hbuf + w * 256 + l * 4);
      float sum = v4.x + v4.y + v4.z + v4.w;
      #pragma unroll
      for (int o = 32; o; o >>= 1) sum += __shfl_xor(sum, o);
      float mean = sum * (1.f / 256.f);
      float dx = v4.x - mean, dy = v4.y - mean, dz = v4.z - mean, dw = v4.w - mean;
      float var = dx * dx + dy * dy + dz * dz + dw * dw;
      #pragma unroll
      for (int o = 32; o; o >>= 1) var += __shfl_xor(var, o);
      float inv = rsqrtf(var * (1.f / 256.f) + 1e-5f);
      const float4 sv = *(const float4*)(ln1_s + l * 4);
      const float4 bv4 = *(const float4*)(ln1_b + l * 4);
      bf16x4 o4;
      o4[0] = f2bf(dx * inv * sv.x + bv4.x);
      o4[1] = f2bf(dy * inv * sv.y + bv4.y);
      o4[2] = f2bf(dz * inv * sv.z + bv4.z);
      o4[3] = f2bf(dw * inv * sv.w + bv4.w);
      *(bf16x4*)(Abuf + w * ASTR + l * 4) = o4;
    }
    __syncthreads();
    {  // QKV layer 0: wave w -> cols w*96..+95
      f32x4 acc[6] = {};
      int nb = w * 96;
      for (int k0 = 0; k0 < 256; k0 += 32) {
        bf16x8 af = *(const bf16x8*)(Abuf + lr * ASTR + k0 + lk * 8);
        #pragma unroll
        for (int t = 0; t < 6; t++) {
          bf16x8 bfr = *(const bf16x8*)(Aqkv + (nb + t * 16 + lr) * 256 + k0 + lk * 8);
          acc[t] = __builtin_amdgcn_mfma_f32_16x16x32_bf16(af, bfr, acc[t], 0, 0, 0);
        }
      }
      #pragma unroll
      for (int t = 0; t < 6; t++) {
        int n = nb + t * 16 + lr;
        #pragma unroll
        for (int r = 0; r < 4; r++) {
          int m = lk * 4 + r;
          if (m < 8) {
            int gm = m0 + m;
            float v = acc[t][r];
            if (n < 256) {
              q_bf[((n >> 5) * 512 + gm) * 32 + (n & 31)] = f2bf(v + bq[n] * QSCALE);
            } else if (n < 512) {
              int nn = n - 256;
              k_bf[((nn >> 5) * 512 + gm) * 32 + (nn & 31)] = f2bf(v + bk[nn]);
            } else {
              int nn = n - 512;
              vT_bf[nn * 512 + gm] = f2bf(v + bv[nn]);
            }
          }
        }
      }
    }
  }
  GBAR();

  // ================= layers =================================================
  for (int layer = 0; layer < NLAYER; ++layer) {
    const short* AoT_l  = AoT + layer * 65536;
    const short* A1T_l  = A1T + layer * 65536;
    const short* A2T_l  = A2T + layer * 65536;

    // ---- X: attention, 2 (head, rowtile16) units per block ----
    {
      int unit = tid >> 8, tu = tid & 255, wu = w & 3;
      int hrt = bid * 2 + unit;
      int head = hrt >> 5, rt = hrt & 31;
      short* Sb = (short*)lds_raw + unit * (16 * 520);
      bf16x8 aq = *(const bf16x8*)(q_bf + (head * 512 + rt * 16 + lr) * 32 + lk * 8);
      #pragma unroll 2
      for (int j = 0; j < 8; j++) {
        int node0 = wu * 128 + j * 16;
        bf16x8 bk8 = *(const bf16x8*)(k_bf + (head * 512 + node0 + lr) * 32 + lk * 8);
        f32x4 s = {};
        s = __builtin_amdgcn_mfma_f32_16x16x32_bf16(aq, bk8, s, 0, 0, 0);
        int gnode = node0 + lr;
        #pragma unroll
        for (int r = 0; r < 4; r++) {
          int row = lk * 4 + r;
          float logit = s[r] + bf2f(bias_bf[(head * 512 + rt * 16 + row) * 512 + gnode]);
          Sb[row * 520 + gnode] = f2bf(logit);
        }
      }
      __syncthreads();
      {
        int row = tu >> 4, j = tu & 15;
        short* Srow = Sb + row * 520;
        float mx = -1e30f;
        #pragma unroll 8
        for (int t = 0; t < 32; t++) mx = fmaxf(mx, bf2f(Srow[j + t * 16]));
        #pragma unroll
        for (int o = 8; o; o >>= 1) mx = fmaxf(mx, __shfl_xor(mx, o, 16));
        float sum = 0.f;
        #pragma unroll 8
        for (int t = 0; t < 32; t++) sum += __expf(bf2f(Srow[j + t * 16]) - mx);
        #pragma unroll
        for (int o = 8; o; o >>= 1) sum += __shfl_xor(sum, o, 16);
        float inv = 1.f / sum;
        #pragma unroll 8
        for (int t = 0; t < 32; t++)
          Srow[j + t * 16] = f2bf(__expf(bf2f(Srow[j + t * 16]) - mx) * inv);
      }
      __syncthreads();
      if (wu < 2) {
        int dh = wu;
        f32x4 oc = {};
        #pragma unroll 4
        for (int ch = 0; ch < 16; ch++) {
          bf16x8 ap = *(const bf16x8*)(Sb + lr * 520 + ch * 32 + lk * 8);
          bf16x8 bv8 = *(const bf16x8*)(vT_bf + (head * 32 + dh * 16 + lr) * 512 + ch * 32 + lk * 8);
          oc = __builtin_amdgcn_mfma_f32_16x16x32_bf16(ap, bv8, oc, 0, 0, 0);
        }
        #pragma unroll
        for (int r = 0; r < 4; r++)
          o_bf[(rt * 16 + lk * 4 + r) * 256 + head * 32 + dh * 16 + lr] = f2bf(oc[r]);
      }
    }
    GBAR();

    // ---- Y: row-local tail, 4 rows per block ----
    {
      int m0 = bid * 4;
      short* Abuf = (short*)lds_raw;                  // [16][ASTR]
      short* Bbuf = (short*)(lds_raw + 8448);         // [16][ASTR]
      float* hbuf = (float*)(lds_raw + 16896);        // [4][256]
      for (int i = tid; i < 792; i += 512) {
        bf16x8 z = {};
        if (i < 396) *(bf16x8*)(Abuf + 4 * ASTR + i * 8) = z;
        else         *(bf16x8*)(Bbuf + 4 * ASTR + (i - 396) * 8) = z;
      }
      if (tid < 128) {
        int row = tid >> 5, j = tid & 31;
        *(bf16x8*)(Abuf + row * ASTR + j * 8) =
            *(const bf16x8*)(o_bf + (m0 + row) * 256 + j * 8);
      }
      __syncthreads();
      // O-proj + residual
      {
        f32x4 acc[2] = {};
        int nb = w * 32;
        for (int k0 = 0; k0 < 256; k0 += 32) {
          bf16x8 af = *(const bf16x8*)(Abuf + lr * ASTR + k0 + lk * 8);
          bf16x8 b0 = *(const bf16x8*)(AoT_l + (nb + lr) * 256 + k0 + lk * 8);
          bf16x8 b1f = *(const bf16x8*)(AoT_l + (nb + 16 + lr) * 256 + k0 + lk * 8);
          acc[0] = __builtin_amdgcn_mfma_f32_16x16x32_bf16(af, b0, acc[0], 0, 0, 0);
          acc[1] = __builtin_amdgcn_mfma_f32_16x16x32_bf16(af, b1f, acc[1], 0, 0, 0);
        }
        const float* bo_l = bo + layer * HD;
        #pragma unroll
        for (int t = 0; t < 2; t++) {
          int n = nb + t * 16 + lr;
          #pragma unroll
          for (int r = 0; r < 4; r++) {
            int m = lk * 4 + r;
            if (m < 4) {
              float hv = h[(m0 + m) * 256 + n] + acc[t][r] + bo_l[n];
              hbuf[m * 256 + n] = hv;
              h[(m0 + m) * 256 + n] = hv;
            }
          }
        }
      }
      __syncthreads();
      // LN2 (waves 0-3)
      if (w < 4) {
        float4 v4 = *(const float4*)(hbuf + w * 256 + l * 4);
        float sum = v4.x + v4.y + v4.z + v4.w;
        #pragma unroll
        for (int o = 32; o; o >>= 1) sum += __shfl_xor(sum, o);
        float mean = sum * (1.f / 256.f);
        float dx = v4.x - mean, dy = v4.y - mean, dz = v4.z - mean, dw = v4.w - mean;
        float var = dx * dx + dy * dy + dz * dz + dw * dw;
        #pragma unroll
        for (int o = 32; o; o >>= 1) var += __shfl_xor(var, o);
        float inv = rsqrtf(var * (1.f / 256.f) + 1e-5f);
        const float* s = ln2_s + layer * HD;
        const float* b = ln2_b + layer * HD;
        const float4 sv = *(const float4*)(s + l * 4);
        const float4 bv4 = *(const float4*)(b + l * 4);
        bf16x4 o4;
        o4[0] = f2bf(dx * inv * sv.x + bv4.x);
        o4[1] = f2bf(dy * inv * sv.y + bv4.y);
        o4[2] = f2bf(dz * inv * sv.z + bv4.z);
        o4[3] = f2bf(dw * inv * sv.w + bv4.w);
        *(bf16x4*)(Abuf + w * ASTR + l * 4) = o4;
      }
      __syncthreads();
      // FFN1 + gelu
      {
        f32x4 acc[2] = {};
        int nb = w * 32;
        for (int k0 = 0; k0 < 256; k0 += 32) {
          bf16x8 af = *(const bf16x8*)(Abuf + lr * ASTR + k0 + lk * 8);
          bf16x8 b0 = *(const bf16x8*)(A1T_l + (nb + lr) * 256 + k0 + lk * 8);
          bf16x8 b1f = *(const bf16x8*)(A1T_l + (nb + 16 + lr) * 256 + k0 + lk * 8);
          acc[0] = __builtin_amdgcn_mfma_f32_16x16x32_bf16(af, b0, acc[0], 0, 0, 0);
          acc[1] = __builtin_amdgcn_mfma_f32_16x16x32_bf16(af, b1f, acc[1], 0, 0, 0);
        }
        const float* b1_l = b1 + layer * HD;
        #pragma unroll
        for (int t = 0; t < 2; t++) {
          int n = nb + t * 16 + lr;
          #pragma unroll
          for (int r = 0; r < 4; r++) {
            int m = lk * 4 + r;
            if (m < 4) {
              float val = acc[t][r] + b1_l[n];
              Bbuf[m * ASTR + n] =
                  f2bf(0.5f * val * (1.f + erff(val * 0.70710678118654752f)));
            }
          }
        }
      }
      __syncthreads();
      // FFN2 + residual
      {
        f32x4 acc[2] = {};
        int nb = w * 32;
        for (int k0 = 0; k0 < 256; k0 += 32) {
          bf16x8 af = *(const bf16x8*)(Bbuf + lr * ASTR + k0 + lk * 8);
          bf16x8 b0 = *(const bf16x8*)(A2T_l + (nb + lr) * 256 + k0 + lk * 8);
          bf16x8 b1f = *(const bf16x8*)(A2T_l + (nb + 16 + lr) * 256 + k0 + lk * 8);
          acc[0] = __builtin_amdgcn_mfma_f32_16x16x32_bf16(af, b0, acc[0], 0, 0, 0);
          acc[1] = __builtin_amdgcn_mfma_f32_16x16x32_bf16(af, b1f, acc[1], 0, 0, 0);
        }
        const float* b2_l = b2 + layer * HD;
        #pragma unroll
        for (int t = 0; t < 2; t++) {
          int n = nb + t * 16 + lr;
          #pragma unroll
          for (int r = 0; r < 4; r++) {
            int m = lk * 4 + r;
            if (m < 4) {
              float hv = hbuf[m * 256 + n] + acc[t][r] + b2_l[n];
              h[(m0 + m) * 256 + n] = hv;
              hbuf[m * 256 + n] = hv;
            }
          }
        }
      }
      if (layer < NLAYER - 1) {
        __syncthreads();
        // LN1 next (waves 0-3)
        if (w < 4) {
          float4 v4 = *(const float4*)(hbuf + w * 256 + l * 4);
          float sum = v4.x + v4.y + v4.z + v4.w;
          #pragma unroll
          for (int o = 32; o; o >>= 1) sum += __shfl_xor(sum, o);
          float mean = sum * (1.f / 256.f);
          float dx = v4.x - mean, dy = v4.y - mean, dz = v4.z - mean, dw = v4.w - mean;
          float var = dx * dx + dy * dy + dz * dz + dw * dw;
          #pragma unroll
          for (int o = 32; o; o >>= 1) var += __shfl_xor(var, o);
          float inv = rsqrtf(var * (1.f / 256.f) + 1e-5f);
          const float* s = ln1_s + (layer + 1) * HD;
          const float* b = ln1_b + (layer + 1) * HD;
          const float4 sv = *(const float4*)(s + l * 4);
          const float4 bv4 = *(const float4*)(b + l * 4);
          bf16x4 o4;
          o4[0] = f2bf(dx * inv * sv.x + bv4.x);
          o4[1] = f2bf(dy * inv * sv.y + bv4.y);
          o4[2] = f2bf(dz * inv * sv.z + bv4.z);
          o4[3] = f2bf(dw * inv * sv.w + bv4.w);
          *(bf16x4*)(Abuf + w * ASTR + l * 4) = o4;
        }
        __syncthreads();
        // QKV next layer
        {
          const short* Aqkv_n = Aqkv + (layer + 1) * 196608;
          const float* bq_n = bq + (layer + 1) * HD;
          const float* bk_n = bk + (layer + 1) * HD;
          const float* bv_n = bv + (layer + 1) * HD;
          f32x4 acc[6] = {};
          int nb = w * 96;
          for (int k0 = 0; k0 < 256; k0 += 32) {
            bf16x8 af = *(const bf16x8*)(Abuf + lr * ASTR + k0 + lk * 8);
            #pragma unroll
            for (int t = 0; t < 6; t++) {
              bf16x8 bfr = *(const bf16x8*)(Aqkv_n + (nb + t * 16 + lr) * 256 + k0 + lk * 8);
              acc[t] = __builtin_amdgcn_mfma_f32_16x16x32_bf16(af, bfr, acc[t], 0, 0, 0);
            }
          }
          #pragma unroll
          for (int t = 0; t < 6; t++) {
            int n = nb + t * 16 + lr;
            #pragma unroll
            for (int r = 0; r < 4; r++) {
              int m = lk * 4 + r;
              if (m < 4) {
                int gm = m0 + m;
                float v = acc[t][r];
                if (n < 256) {
                  q_bf[((n >> 5) * 512 + gm) * 32 + (n & 31)] = f2bf(v + bq_n[n] * QSCALE);
                } else if (n < 512) {
                  int nn = n - 256;
                  k_bf[((nn >> 5) * 512 + gm) * 32 + (nn & 31)] = f2bf(v + bk_n[nn]);
                } else {
                  int nn = n - 512;
                  vT_bf[nn * 512 + gm] = f2bf(v + bv_n[nn]);
                }
              }
            }
          }
        }
        GBAR();
      }
    }
  }
}

extern "C" void kernel_launch(void* const* d_in, const int* in_sizes, int n_in,
                              void* d_out, int out_size, void* d_ws, size_t ws_size,
                              hipStream_t stream) {
  const float* x             = (const float*)d_in[0];
  const int*   edge_encodes  = (const int*)d_in[2];
  const int*   edge_dist_enc = (const int*)d_in[3];
  const float* W_feat = (const float*)d_in[7];
  const float* b_feat = (const float*)d_in[8];
  const float* edge_emb      = (const float*)d_in[9];
  const float* edge_dist_emb = (const float*)d_in[10];
  const float* W_ee = (const float*)d_in[11];
  const float* b_ee = (const float*)d_in[12];
  const float* W_ed = (const float*)d_in[13];
  const float* b_ed = (const float*)d_in[14];
  const float* ln1_s = (const float*)d_in[15];
  const float* ln1_b = (const float*)d_in[16];
  const float* Wq = (const float*)d_in[17];
  const float* bq = (const float*)d_in[18];
  const float* Wk = (const float*)d_in[19];
  const float* bk = (const float*)d_in[20];
  const float* Wv = (const float*)d_in[21];
  const float* bv = (const float*)d_in[22];
  const float* Wo = (const float*)d_in[23];
  const float* bo = (const float*)d_in[24];
  const float* ln2_s = (const float*)d_in[25];
  const float* ln2_b = (const float*)d_in[26];
  const float* W1 = (const float*)d_in[27];
  const float* b1 = (const float*)d_in[28];
  const float* W2 = (const float*)d_in[29];
  const float* b2 = (const float*)d_in[30];

  float* h = (float*)d_out;
  char* base = (char*)d_ws;
  short* bias_bf = (short*)base;                       // 4 MB
  short* Aqkv = (short*)(base + 4194304);
  short* AoT  = (short*)(base + 6553600);
  short* A1T  = (short*)(base + 7340032);
  short* A2T  = (short*)(base + 8126464);
  short* WfT  = (short*)(base + 8912896);
  short* q_bf = (short*)(base + 9043968);
  short* k_bf = (short*)(base + 9306112);
  short* vT_bf= (short*)(base + 9568256);
  short* o_bf = (short*)(base + 9830400);
  float* eeP  = (float*)(base + 10092544);
  float* edP  = (float*)(base + 10093568);
  unsigned* bar = (unsigned*)(base + 10097664);        // flags[128*16] + gen

  hipMemsetAsync(bar, 0, 128 * 64 + 64, stream);
  mono_kernel<<<NBLK, 512, 0, stream>>>(
      x, edge_encodes, edge_dist_enc, W_feat, b_feat,
      edge_emb, edge_dist_emb, W_ee, b_ee, W_ed, b_ed,
      ln1_s, ln1_b, Wq, bq, Wk, bk, Wv, bv, Wo, bo,
      ln2_s, ln2_b, W1, b1, W2, b2,
      h, bias_bf, Aqkv, AoT, A1T, A2T, WfT,
      q_bf, k_bf, vT_bf, o_bf, eeP, edP,
      bar, bar + 128 * 16);
}

// Round 9
// 292.275 us; speedup vs baseline: 1.6302x; 1.4015x over previous
//
#include <hip/hip_runtime.h>
#include <math.h>

#define NN 512
#define HD 256
#define NLAYER 6
#define QSCALE 0.17677669529663687f
#define ASTR 264   // padded activation LDS stride (shorts)

typedef __attribute__((ext_vector_type(8))) short bf16x8;
typedef __attribute__((ext_vector_type(4))) short bf16x4;
typedef __attribute__((ext_vector_type(4))) float f32x4;

__device__ __forceinline__ short f2bf(float f) {
  union { float f; unsigned u; } v; v.f = f;
  unsigned r = (v.u + 0x7FFFu + ((v.u >> 16) & 1u)) >> 16;
  return (short)r;
}
__device__ __forceinline__ float bf2f(short s) {
  union { unsigned u; float f; } v; v.u = ((unsigned)(unsigned short)s) << 16;
  return v.f;
}

__device__ __forceinline__ float blk_sum(float v) {
  __shared__ float sb[4];
  #pragma unroll
  for (int o = 32; o; o >>= 1) v += __shfl_down(v, o, 64);
  if ((threadIdx.x & 63) == 0) sb[threadIdx.x >> 6] = v;
  __syncthreads();
  v = sb[0] + sb[1] + sb[2] + sb[3];
  __syncthreads();
  return v;
}

// ---------- per-table-row projections (rows 0..31 ee, 32..159 ed) ----------
__global__ __launch_bounds__(256) void proj_kernel(
    const float* __restrict__ edge_emb, const float* __restrict__ edge_dist_emb,
    const float* __restrict__ W_ee, const float* __restrict__ W_ed,
    float* __restrict__ eeP, float* __restrict__ edP) {
  int r = blockIdx.x;
  const float* table; const float* W; float* out; int row;
  if (r < 32) { table = edge_emb;      W = W_ee; out = eeP; row = r; }
  else        { table = edge_dist_emb; W = W_ed; out = edP; row = r - 32; }
  int t = threadIdx.x;
  float val = table[row * HD + t];
  float ss = blk_sum(val * val);
  float n = sqrtf(ss);
  float sc = (n > 1.f) ? 1.f / (n + 1e-7f) : 1.f;
  float v = val * sc;
  #pragma unroll
  for (int hh = 0; hh < 8; hh++) {
    float p = blk_sum(v * W[t * 8 + hh]);
    if (t == 0) out[row * 8 + hh] = p;
  }
}

// ---------- build attn_bias [NH][N][N] bf16 ----------
__global__ __launch_bounds__(256) void bias_kernel(
    const int* __restrict__ ee, const int* __restrict__ ed,
    const float* __restrict__ eeP, const float* __restrict__ edP,
    const float* __restrict__ b_ee, const float* __restrict__ b_ed,
    short* __restrict__ bias) {
  __shared__ float seeP[32 * 8];
  __shared__ float sedP[128 * 8];
  __shared__ float sbe[8], sbd[8];
  int t = threadIdx.x;
  seeP[t] = eeP[t];
  #pragma unroll
  for (int i = 0; i < 4; i++) sedP[t + i * 256] = edP[t + i * 256];
  if (t < 8) { sbe[t] = b_ee[t]; sbd[t] = b_ed[t]; }
  __syncthreads();
  int idx = blockIdx.x * 256 + t;
  int e0 = ee[idx * 2], e1 = ee[idx * 2 + 1];
  int d = ed[idx];
  #pragma unroll
  for (int hh = 0; hh < 8; hh++) {
    bias[hh * (NN * NN) + idx] = f2bf(
        0.5f * (seeP[e0 * 8 + hh] + seeP[e1 * 8 + hh]) + sbe[hh]
        + sedP[d * 8 + hh] + sbd[hh]);
  }
}

// ---------- transpose+cast weights to bf16 WT[n][k] ----------
__global__ __launch_bounds__(256) void wcast_kernel(
    const float* __restrict__ Wq, const float* __restrict__ Wk,
    const float* __restrict__ Wv, const float* __restrict__ Wo,
    const float* __restrict__ W1, const float* __restrict__ W2,
    const float* __restrict__ Wf,
    short* __restrict__ Aqkv, short* __restrict__ AoT,
    short* __restrict__ A1T, short* __restrict__ A2T, short* __restrict__ WfT) {
  __shared__ float tile[32][33];
  int b = blockIdx.x;
  const float* src; short* dst; float scl = 1.f;
  int t;
  if (b < 2304) {
    int l = b / 384; int rr = b % 384; int mat = rr / 64; t = rr % 64;
    if      (mat == 0) { src = Wq + l * 65536; dst = Aqkv + l * 196608; scl = QSCALE; }
    else if (mat == 1) { src = Wk + l * 65536; dst = Aqkv + l * 196608 + 65536; }
    else if (mat == 2) { src = Wv + l * 65536; dst = Aqkv + l * 196608 + 131072; }
    else if (mat == 3) { src = Wo + l * 65536; dst = AoT + l * 65536; }
    else if (mat == 4) { src = W1 + l * 65536; dst = A1T + l * 65536; }
    else               { src = W2 + l * 65536; dst = A2T + l * 65536; }
  } else {
    src = Wf; dst = WfT; t = b - 2304;
  }
  int tr = t >> 3, tc = t & 7;
  int tid = threadIdx.x;
  int kl = tid >> 3, nl4 = (tid & 7) * 4;
  float4 v = *(const float4*)(src + (tr * 32 + kl) * 256 + tc * 32 + nl4);
  tile[kl][nl4 + 0] = v.x; tile[kl][nl4 + 1] = v.y;
  tile[kl][nl4 + 2] = v.z; tile[kl][nl4 + 3] = v.w;
  __syncthreads();
  int nl = tid >> 3, kl4 = (tid & 7) * 4;
  bf16x4 o;
  #pragma unroll
  for (int i = 0; i < 4; i++) o[i] = f2bf(tile[kl4 + i][nl] * scl);
  *(bf16x4*)(dst + (tc * 32 + nl) * 256 + tr * 32 + kl4) = o;
}

// ---------- feat + LN1 + QKV layer0: 64 blocks x 512, 8 rows/block ----------
__global__ __launch_bounds__(512) void featqkv_kernel(
    const float* __restrict__ x, const short* __restrict__ WfT,
    const float* __restrict__ b_feat, float* __restrict__ h,
    const float* __restrict__ ln1_s, const float* __restrict__ ln1_b,
    const short* __restrict__ Aqkv, const float* __restrict__ bq,
    const float* __restrict__ bk, const float* __restrict__ bv,
    short* __restrict__ q_bf, short* __restrict__ k_bf, short* __restrict__ vT_bf) {
  __shared__ __align__(16) short Abuf[16 * ASTR];
  __shared__ __align__(16) float hbuf[8 * 256];
  int tid = threadIdx.x, w = tid >> 6, l = tid & 63, lr = l & 15, lk = l >> 4;
  int m0 = blockIdx.x * 8;
  if (tid < 264) {
    bf16x8 z = {};
    *(bf16x8*)(Abuf + 8 * ASTR + tid * 8) = z;   // zero rows 8..15
  }
  {
    int row = tid >> 6, j = tid & 63;
    float4 v = *(const float4*)(x + (m0 + row) * 256 + j * 4);
    bf16x4 o4; o4[0] = f2bf(v.x); o4[1] = f2bf(v.y); o4[2] = f2bf(v.z); o4[3] = f2bf(v.w);
    *(bf16x4*)(Abuf + row * ASTR + j * 4) = o4;
  }
  __syncthreads();
  {
    f32x4 acc[2] = {};
    int nb = w * 32;
    for (int k0 = 0; k0 < 256; k0 += 32) {
      bf16x8 af = *(const bf16x8*)(Abuf + lr * ASTR + k0 + lk * 8);
      bf16x8 b0 = *(const bf16x8*)(WfT + (nb + lr) * 256 + k0 + lk * 8);
      bf16x8 b1f = *(const bf16x8*)(WfT + (nb + 16 + lr) * 256 + k0 + lk * 8);
      acc[0] = __builtin_amdgcn_mfma_f32_16x16x32_bf16(af, b0, acc[0], 0, 0, 0);
      acc[1] = __builtin_amdgcn_mfma_f32_16x16x32_bf16(af, b1f, acc[1], 0, 0, 0);
    }
    #pragma unroll
    for (int t = 0; t < 2; t++) {
      int n = nb + t * 16 + lr;
      #pragma unroll
      for (int r = 0; r < 4; r++) {
        int m = lk * 4 + r;
        if (m < 8) {
          float v = acc[t][r] + b_feat[n];
          hbuf[m * 256 + n] = v;
          h[(m0 + m) * 256 + n] = v;
        }
      }
    }
  }
  __syncthreads();
  {  // LN1: wave w -> row w
    float4 v4 = *(const float4*)(hbuf + w * 256 + l * 4);
    float sum = v4.x + v4.y + v4.z + v4.w;
    #pragma unroll
    for (int o = 32; o; o >>= 1) sum += __shfl_xor(sum, o);
    float mean = sum * (1.f / 256.f);
    float dx = v4.x - mean, dy = v4.y - mean, dz = v4.z - mean, dw = v4.w - mean;
    float var = dx * dx + dy * dy + dz * dz + dw * dw;
    #pragma unroll
    for (int o = 32; o; o >>= 1) var += __shfl_xor(var, o);
    float inv = rsqrtf(var * (1.f / 256.f) + 1e-5f);
    const float4 sv = *(const float4*)(ln1_s + l * 4);
    const float4 bv4 = *(const float4*)(ln1_b + l * 4);
    bf16x4 o4;
    o4[0] = f2bf(dx * inv * sv.x + bv4.x);
    o4[1] = f2bf(dy * inv * sv.y + bv4.y);
    o4[2] = f2bf(dz * inv * sv.z + bv4.z);
    o4[3] = f2bf(dw * inv * sv.w + bv4.w);
    *(bf16x4*)(Abuf + w * ASTR + l * 4) = o4;
  }
  __syncthreads();
  {  // QKV layer 0: wave w -> cols w*96..+95
    f32x4 acc[6] = {};
    int nb = w * 96;
    for (int k0 = 0; k0 < 256; k0 += 32) {
      bf16x8 af = *(const bf16x8*)(Abuf + lr * ASTR + k0 + lk * 8);
      #pragma unroll
      for (int t = 0; t < 6; t++) {
        bf16x8 bfr = *(const bf16x8*)(Aqkv + (nb + t * 16 + lr) * 256 + k0 + lk * 8);
        acc[t] = __builtin_amdgcn_mfma_f32_16x16x32_bf16(af, bfr, acc[t], 0, 0, 0);
      }
    }
    #pragma unroll
    for (int t = 0; t < 6; t++) {
      int n = nb + t * 16 + lr;
      #pragma unroll
      for (int r = 0; r < 4; r++) {
        int m = lk * 4 + r;
        if (m < 8) {
          int gm = m0 + m;
          float v = acc[t][r];
          if (n < 256) {
            q_bf[((n >> 5) * 512 + gm) * 32 + (n & 31)] = f2bf(v + bq[n] * QSCALE);
          } else if (n < 512) {
            int nn = n - 256;
            k_bf[((nn >> 5) * 512 + gm) * 32 + (nn & 31)] = f2bf(v + bk[nn]);
          } else {
            int nn = n - 512;
            vT_bf[nn * 512 + gm] = f2bf(v + bv[nn]);
          }
        }
      }
    }
  }
}

// ---------- attention: 128 blocks x 512, 2 (head, rowtile16) units ----------
__global__ __launch_bounds__(512) void attn_kernel(
    const short* __restrict__ q_bf, const short* __restrict__ k_bf,
    const short* __restrict__ vT_bf, const short* __restrict__ bias_bf,
    short* __restrict__ o_bf) {
  __shared__ __align__(16) short Sb2[2 * 16 * 520];
  int tid = threadIdx.x, bid = blockIdx.x;
  int w = tid >> 6, l = tid & 63, lr = l & 15, lk = l >> 4;
  int unit = tid >> 8, tu = tid & 255, wu = w & 3;
  int hrt = bid * 2 + unit;
  int head = hrt >> 5, rt = hrt & 31;
  short* Sb = Sb2 + unit * (16 * 520);
  bf16x8 aq = *(const bf16x8*)(q_bf + (head * 512 + rt * 16 + lr) * 32 + lk * 8);
  #pragma unroll 2
  for (int j = 0; j < 8; j++) {
    int node0 = wu * 128 + j * 16;
    bf16x8 bk8 = *(const bf16x8*)(k_bf + (head * 512 + node0 + lr) * 32 + lk * 8);
    f32x4 s = {};
    s = __builtin_amdgcn_mfma_f32_16x16x32_bf16(aq, bk8, s, 0, 0, 0);
    int gnode = node0 + lr;
    #pragma unroll
    for (int r = 0; r < 4; r++) {
      int row = lk * 4 + r;
      float logit = s[r] + bf2f(bias_bf[(head * 512 + rt * 16 + row) * 512 + gnode]);
      Sb[row * 520 + gnode] = f2bf(logit);
    }
  }
  __syncthreads();
  {
    int row = tu >> 4, j = tu & 15;
    short* Srow = Sb + row * 520;
    float mx = -1e30f;
    #pragma unroll 8
    for (int t = 0; t < 32; t++) mx = fmaxf(mx, bf2f(Srow[j + t * 16]));
    #pragma unroll
    for (int o = 8; o; o >>= 1) mx = fmaxf(mx, __shfl_xor(mx, o, 16));
    float sum = 0.f;
    #pragma unroll 8
    for (int t = 0; t < 32; t++) sum += __expf(bf2f(Srow[j + t * 16]) - mx);
    #pragma unroll
    for (int o = 8; o; o >>= 1) sum += __shfl_xor(sum, o, 16);
    float inv = 1.f / sum;
    #pragma unroll 8
    for (int t = 0; t < 32; t++)
      Srow[j + t * 16] = f2bf(__expf(bf2f(Srow[j + t * 16]) - mx) * inv);
  }
  __syncthreads();
  if (wu < 2) {
    int dh = wu;
    f32x4 oc = {};
    #pragma unroll 4
    for (int ch = 0; ch < 16; ch++) {
      bf16x8 ap = *(const bf16x8*)(Sb + lr * 520 + ch * 32 + lk * 8);
      bf16x8 bv8 = *(const bf16x8*)(vT_bf + (head * 32 + dh * 16 + lr) * 512 + ch * 32 + lk * 8);
      oc = __builtin_amdgcn_mfma_f32_16x16x32_bf16(ap, bv8, oc, 0, 0, 0);
    }
    #pragma unroll
    for (int r = 0; r < 4; r++)
      o_bf[(rt * 16 + lk * 4 + r) * 256 + head * 32 + dh * 16 + lr] = f2bf(oc[r]);
  }
}

// ---------- tail: 128 blocks x 512, 4 rows/block ----------
__global__ __launch_bounds__(512) void tail_kernel(
    const short* __restrict__ o_bf, float* __restrict__ h,
    const short* __restrict__ AoT_l, const float* __restrict__ bo_l,
    const float* __restrict__ ln2_s, const float* __restrict__ ln2_b,
    const short* __restrict__ A1T_l, const float* __restrict__ b1_l,
    const short* __restrict__ A2T_l, const float* __restrict__ b2_l,
    const float* __restrict__ ln1n_s, const float* __restrict__ ln1n_b,
    const short* __restrict__ Aqkv_n, const float* __restrict__ bq_n,
    const float* __restrict__ bk_n, const float* __restrict__ bv_n,
    short* __restrict__ q_bf, short* __restrict__ k_bf, short* __restrict__ vT_bf,
    int last) {
  __shared__ __align__(16) short Abuf[16 * ASTR];
  __shared__ __align__(16) short Bbuf[16 * ASTR];
  __shared__ __align__(16) float hbuf[4 * 256];
  int tid = threadIdx.x, bid = blockIdx.x;
  int w = tid >> 6, l = tid & 63, lr = l & 15, lk = l >> 4;
  int m0 = bid * 4;
  for (int i = tid; i < 792; i += 512) {
    bf16x8 z = {};
    if (i < 396) *(bf16x8*)(Abuf + 4 * ASTR + i * 8) = z;
    else         *(bf16x8*)(Bbuf + 4 * ASTR + (i - 396) * 8) = z;
  }
  if (tid < 128) {
    int row = tid >> 5, j = tid & 31;
    *(bf16x8*)(Abuf + row * ASTR + j * 8) =
        *(const bf16x8*)(o_bf + (m0 + row) * 256 + j * 8);
  }
  __syncthreads();
  // O-proj + residual
  {
    f32x4 acc[2] = {};
    int nb = w * 32;
    for (int k0 = 0; k0 < 256; k0 += 32) {
      bf16x8 af = *(const bf16x8*)(Abuf + lr * ASTR + k0 + lk * 8);
      bf16x8 b0 = *(const bf16x8*)(AoT_l + (nb + lr) * 256 + k0 + lk * 8);
      bf16x8 b1f = *(const bf16x8*)(AoT_l + (nb + 16 + lr) * 256 + k0 + lk * 8);
      acc[0] = __builtin_amdgcn_mfma_f32_16x16x32_bf16(af, b0, acc[0], 0, 0, 0);
      acc[1] = __builtin_amdgcn_mfma_f32_16x16x32_bf16(af, b1f, acc[1], 0, 0, 0);
    }
    #pragma unroll
    for (int t = 0; t < 2; t++) {
      int n = nb + t * 16 + lr;
      #pragma unroll
      for (int r = 0; r < 4; r++) {
        int m = lk * 4 + r;
        if (m < 4) {
          float hv = h[(m0 + m) * 256 + n] + acc[t][r] + bo_l[n];
          hbuf[m * 256 + n] = hv;
          h[(m0 + m) * 256 + n] = hv;
        }
      }
    }
  }
  __syncthreads();
  // LN2 (waves 0-3)
  if (w < 4) {
    float4 v4 = *(const float4*)(hbuf + w * 256 + l * 4);
    float sum = v4.x + v4.y + v4.z + v4.w;
    #pragma unroll
    for (int o = 32; o; o >>= 1) sum += __shfl_xor(sum, o);
    float mean = sum * (1.f / 256.f);
    float dx = v4.x - mean, dy = v4.y - mean, dz = v4.z - mean, dw = v4.w - mean;
    float var = dx * dx + dy * dy + dz * dz + dw * dw;
    #pragma unroll
    for (int o = 32; o; o >>= 1) var += __shfl_xor(var, o);
    float inv = rsqrtf(var * (1.f / 256.f) + 1e-5f);
    const float4 sv = *(const float4*)(ln2_s + l * 4);
    const float4 bv4 = *(const float4*)(ln2_b + l * 4);
    bf16x4 o4;
    o4[0] = f2bf(dx * inv * sv.x + bv4.x);
    o4[1] = f2bf(dy * inv * sv.y + bv4.y);
    o4[2] = f2bf(dz * inv * sv.z + bv4.z);
    o4[3] = f2bf(dw * inv * sv.w + bv4.w);
    *(bf16x4*)(Abuf + w * ASTR + l * 4) = o4;
  }
  __syncthreads();
  // FFN1 + gelu
  {
    f32x4 acc[2] = {};
    int nb = w * 32;
    for (int k0 = 0; k0 < 256; k0 += 32) {
      bf16x8 af = *(const bf16x8*)(Abuf + lr * ASTR + k0 + lk * 8);
      bf16x8 b0 = *(const bf16x8*)(A1T_l + (nb + lr) * 256 + k0 + lk * 8);
      bf16x8 b1f = *(const bf16x8*)(A1T_l + (nb + 16 + lr) * 256 + k0 + lk * 8);
      acc[0] = __builtin_amdgcn_mfma_f32_16x16x32_bf16(af, b0, acc[0], 0, 0, 0);
      acc[1] = __builtin_amdgcn_mfma_f32_16x16x32_bf16(af, b1f, acc[1], 0, 0, 0);
    }
    #pragma unroll
    for (int t = 0; t < 2; t++) {
      int n = nb + t * 16 + lr;
      #pragma unroll
      for (int r = 0; r < 4; r++) {
        int m = lk * 4 + r;
        if (m < 4) {
          float val = acc[t][r] + b1_l[n];
          Bbuf[m * ASTR + n] =
              f2bf(0.5f * val * (1.f + erff(val * 0.70710678118654752f)));
        }
      }
    }
  }
  __syncthreads();
  // FFN2 + residual
  {
    f32x4 acc[2] = {};
    int nb = w * 32;
    for (int k0 = 0; k0 < 256; k0 += 32) {
      bf16x8 af = *(const bf16x8*)(Bbuf + lr * ASTR + k0 + lk * 8);
      bf16x8 b0 = *(const bf16x8*)(A2T_l + (nb + lr) * 256 + k0 + lk * 8);
      bf16x8 b1f = *(const bf16x8*)(A2T_l + (nb + 16 + lr) * 256 + k0 + lk * 8);
      acc[0] = __builtin_amdgcn_mfma_f32_16x16x32_bf16(af, b0, acc[0], 0, 0, 0);
      acc[1] = __builtin_amdgcn_mfma_f32_16x16x32_bf16(af, b1f, acc[1], 0, 0, 0);
    }
    #pragma unroll
    for (int t = 0; t < 2; t++) {
      int n = nb + t * 16 + lr;
      #pragma unroll
      for (int r = 0; r < 4; r++) {
        int m = lk * 4 + r;
        if (m < 4) {
          float hv = hbuf[m * 256 + n] + acc[t][r] + b2_l[n];
          h[(m0 + m) * 256 + n] = hv;
          hbuf[m * 256 + n] = hv;
        }
      }
    }
  }
  if (last) return;
  __syncthreads();
  // LN1 next (waves 0-3)
  if (w < 4) {
    float4 v4 = *(const float4*)(hbuf + w * 256 + l * 4);
    float sum = v4.x + v4.y + v4.z + v4.w;
    #pragma unroll
    for (int o = 32; o; o >>= 1) sum += __shfl_xor(sum, o);
    float mean = sum * (1.f / 256.f);
    float dx = v4.x - mean, dy = v4.y - mean, dz = v4.z - mean, dw = v4.w - mean;
    float var = dx * dx + dy * dy + dz * dz + dw * dw;
    #pragma unroll
    for (int o = 32; o; o >>= 1) var += __shfl_xor(var, o);
    float inv = rsqrtf(var * (1.f / 256.f) + 1e-5f);
    const float4 sv = *(const float4*)(ln1n_s + l * 4);
    const float4 bv4 = *(const float4*)(ln1n_b + l * 4);
    bf16x4 o4;
    o4[0] = f2bf(dx * inv * sv.x + bv4.x);
    o4[1] = f2bf(dy * inv * sv.y + bv4.y);
    o4[2] = f2bf(dz * inv * sv.z + bv4.z);
    o4[3] = f2bf(dw * inv * sv.w + bv4.w);
    *(bf16x4*)(Abuf + w * ASTR + l * 4) = o4;
  }
  __syncthreads();
  // QKV next layer
  {
    f32x4 acc[6] = {};
    int nb = w * 96;
    for (int k0 = 0; k0 < 256; k0 += 32) {
      bf16x8 af = *(const bf16x8*)(Abuf + lr * ASTR + k0 + lk * 8);
      #pragma unroll
      for (int t = 0; t < 6; t++) {
        bf16x8 bfr = *(const bf16x8*)(Aqkv_n + (nb + t * 16 + lr) * 256 + k0 + lk * 8);
        acc[t] = __builtin_amdgcn_mfma_f32_16x16x32_bf16(af, bfr, acc[t], 0, 0, 0);
      }
    }
    #pragma unroll
    for (int t = 0; t < 6; t++) {
      int n = nb + t * 16 + lr;
      #pragma unroll
      for (int r = 0; r < 4; r++) {
        int m = lk * 4 + r;
        if (m < 4) {
          int gm = m0 + m;
          float v = acc[t][r];
          if (n < 256) {
            q_bf[((n >> 5) * 512 + gm) * 32 + (n & 31)] = f2bf(v + bq_n[n] * QSCALE);
          } else if (n < 512) {
            int nn = n - 256;
            k_bf[((nn >> 5) * 512 + gm) * 32 + (nn & 31)] = f2bf(v + bk_n[nn]);
          } else {
            int nn = n - 512;
            vT_bf[nn * 512 + gm] = f2bf(v + bv_n[nn]);
          }
        }
      }
    }
  }
}

extern "C" void kernel_launch(void* const* d_in, const int* in_sizes, int n_in,
                              void* d_out, int out_size, void* d_ws, size_t ws_size,
                              hipStream_t stream) {
  const float* x             = (const float*)d_in[0];
  const int*   edge_encodes  = (const int*)d_in[2];
  const int*   edge_dist_enc = (const int*)d_in[3];
  const float* W_feat = (const float*)d_in[7];
  const float* b_feat = (const float*)d_in[8];
  const float* edge_emb      = (const float*)d_in[9];
  const float* edge_dist_emb = (const float*)d_in[10];
  const float* W_ee = (const float*)d_in[11];
  const float* b_ee = (const float*)d_in[12];
  const float* W_ed = (const float*)d_in[13];
  const float* b_ed = (const float*)d_in[14];
  const float* ln1_s = (const float*)d_in[15];
  const float* ln1_b = (const float*)d_in[16];
  const float* Wq = (const float*)d_in[17];
  const float* bq = (const float*)d_in[18];
  const float* Wk = (const float*)d_in[19];
  const float* bk = (const float*)d_in[20];
  const float* Wv = (const float*)d_in[21];
  const float* bv = (const float*)d_in[22];
  const float* Wo = (const float*)d_in[23];
  const float* bo = (const float*)d_in[24];
  const float* ln2_s = (const float*)d_in[25];
  const float* ln2_b = (const float*)d_in[26];
  const float* W1 = (const float*)d_in[27];
  const float* b1 = (const float*)d_in[28];
  const float* W2 = (const float*)d_in[29];
  const float* b2 = (const float*)d_in[30];

  float* h = (float*)d_out;
  char* base = (char*)d_ws;
  short* bias_bf = (short*)base;                       // 4 MB
  short* Aqkv = (short*)(base + 4194304);
  short* AoT  = (short*)(base + 6553600);
  short* A1T  = (short*)(base + 7340032);
  short* A2T  = (short*)(base + 8126464);
  short* WfT  = (short*)(base + 8912896);
  short* q_bf = (short*)(base + 9043968);
  short* k_bf = (short*)(base + 9306112);
  short* vT_bf= (short*)(base + 9568256);
  short* o_bf = (short*)(base + 9830400);
  float* eeP  = (float*)(base + 10092544);
  float* edP  = (float*)(base + 10093568);

  wcast_kernel<<<2368, 256, 0, stream>>>(Wq, Wk, Wv, Wo, W1, W2, W_feat,
                                         Aqkv, AoT, A1T, A2T, WfT);
  proj_kernel<<<160, 256, 0, stream>>>(edge_emb, edge_dist_emb, W_ee, W_ed, eeP, edP);
  bias_kernel<<<1024, 256, 0, stream>>>(edge_encodes, edge_dist_enc, eeP, edP,
                                        b_ee, b_ed, bias_bf);
  featqkv_kernel<<<64, 512, 0, stream>>>(x, WfT, b_feat, h,
                                         ln1_s, ln1_b, Aqkv, bq, bk, bv,
                                         q_bf, k_bf, vT_bf);
  for (int l = 0; l < NLAYER; l++) {
    attn_kernel<<<128, 512, 0, stream>>>(q_bf, k_bf, vT_bf, bias_bf, o_bf);
    int ln = (l < NLAYER - 1) ? l + 1 : l;
    tail_kernel<<<128, 512, 0, stream>>>(
        o_bf, h,
        AoT + l * 65536, bo + l * HD,
        ln2_s + l * HD, ln2_b + l * HD,
        A1T + l * 65536, b1 + l * HD,
        A2T + l * 65536, b2 + l * HD,
        ln1_s + ln * HD, ln1_b + ln * HD,
        Aqkv + ln * 196608, bq + ln * HD, bk + ln * HD, bv + ln * HD,
        q_bf, k_bf, vT_bf, l == NLAYER - 1);
  }
}